// Round 4
// baseline (563.926 us; speedup 1.0000x reference)
//
#include <hip/hip_runtime.h>

#define NN 100000
#define NE 1600000
#define HF 128
#define NC 64
#define AP 136      // padded LDS row (bf16 elems): 272B stride, 16B-aligned chunks
#define NB 196      // edge buckets: ceil(100000/512)
#define BSH 9       // 512 nodes per bucket
#define BMASK 511
#define BCAP 9216   // fixed bucket capacity (~12 sigma above mean 8163)

typedef __bf16 bf16x8 __attribute__((ext_vector_type(8)));
typedef float  f32x4  __attribute__((ext_vector_type(4)));
typedef unsigned short us8 __attribute__((ext_vector_type(8)));

__device__ __forceinline__ unsigned short f2b(float x) {
  unsigned int u = __float_as_uint(x);
  u += 0x7FFFu + ((u >> 16) & 1u);   // RNE
  return (unsigned short)(u >> 16);
}
__device__ __forceinline__ float b2f(unsigned short b) {
  return __uint_as_float(((unsigned int)b) << 16);
}

// ---------------- weight prep: bf16 W^T + folded BN affine ----------------
__global__ void prep_weights(const float* __restrict__ conv_w, const float* __restrict__ conv_b,
                             const float* __restrict__ bn_g, const float* __restrict__ bn_b,
                             const float* __restrict__ bn_m, const float* __restrict__ bn_v,
                             const float* __restrict__ fc_w,
                             unsigned short* __restrict__ wt, unsigned short* __restrict__ wtf,
                             float* __restrict__ sarr, float* __restrict__ tarr) {
  int idx = blockIdx.x * 256 + threadIdx.x;
  if (idx < 6 * HF * HF) {
    int ls = idx / (HF * HF);
    int rem = idx - ls * HF * HF;
    int k = rem >> 7;          // input feature
    int n = rem & 127;         // output feature
    wt[(ls * HF + n) * HF + k] = f2b(conv_w[idx]);   // store W^T: [n][k]
  }
  if (idx < HF * NC) {
    int k = idx >> 6;
    int c = idx & 63;
    wtf[c * HF + k] = f2b(fc_w[idx]);                // fc W^T: [c][k]
  }
  if (idx < 6 * HF) {
    float s = bn_g[idx] * rsqrtf(bn_v[idx] + 1e-5f);
    sarr[idx] = s;
    tarr[idx] = (conv_b[idx] - bn_m[idx]) * s + bn_b[idx];  // fold linear bias into BN shift
  }
}

// ---------------- cast x fp32 -> bf16 ----------------
__global__ __launch_bounds__(256) void cast_bf16(const float* __restrict__ x,
                                                 unsigned short* __restrict__ xb) {
  size_t i = (size_t)(blockIdx.x * 256 + threadIdx.x) * 8;
  float4 a = *(const float4*)(x + i);
  float4 b = *(const float4*)(x + i + 4);
  us8 v = { f2b(a.x), f2b(a.y), f2b(a.z), f2b(a.w),
            f2b(b.x), f2b(b.y), f2b(b.z), f2b(b.w) };
  *(us8*)(xb + i) = v;
}

// ---------------- gcur init: fixed-capacity bucket bases ----------------
__global__ void init_gcur(int* __restrict__ gcur) {
  int t = threadIdx.x;
  if (t < NB) gcur[t] = t * BCAP;
}

// ---------------- bin edges into fixed-capacity buckets ----------------
// entry = src (17 bits) | dst_local (9 bits) << 17
__global__ __launch_bounds__(256) void bin_edges(const int* __restrict__ src,
                                                 const int* __restrict__ dst,
                                                 int* __restrict__ gcur,
                                                 unsigned int* __restrict__ binned) {
  __shared__ int hist[NB];
  int t = threadIdx.x;
  if (t < NB) hist[t] = 0;
  __syncthreads();
  int base = blockIdx.x * 8192;
  for (int j = 0; j < 32; j++) {
    int e = base + j * 256 + t;
    if (e < NE) atomicAdd(&hist[dst[e] >> BSH], 1);
  }
  __syncthreads();
  if (t < NB) {                       // reserve contiguous range in this bucket
    int c = hist[t];
    if (c) hist[t] = atomicAdd(&gcur[t], c);
  }
  __syncthreads();
  for (int j = 0; j < 32; j++) {
    int e = base + j * 256 + t;
    if (e < NE) {
      int d = dst[e];
      int b = d >> BSH;
      int p = atomicAdd(&hist[b], 1);
      binned[p] = (unsigned int)src[e] | ((unsigned int)(d & BMASK) << 17);
    }
  }
}

// ---------------- per-bucket CSR build: offs + deg + csr (L2-local scatter) ----
__global__ __launch_bounds__(256) void build_csr(const unsigned int* __restrict__ binned,
                                                 const int* __restrict__ gcur,
                                                 int* __restrict__ offs,
                                                 int* __restrict__ deg,
                                                 int* __restrict__ csr) {
  __shared__ int ncnt[512];
  __shared__ int sm[256];
  int t = threadIdx.x;
  int b = blockIdx.x;
  int beg = b * BCAP;
  int cntb = gcur[b] - beg;
  ncnt[t] = 0; ncnt[t + 256] = 0;
  __syncthreads();
  for (int e = beg + t; e < beg + cntb; e += 256) atomicAdd(&ncnt[binned[e] >> 17], 1);
  __syncthreads();
  int c0 = ncnt[2 * t], c1 = ncnt[2 * t + 1];
  int s = c0 + c1;
  sm[t] = s; __syncthreads();
  for (int off = 1; off < 256; off <<= 1) {
    int u = (t >= off) ? sm[t - off] : 0;
    __syncthreads();
    sm[t] += u;
    __syncthreads();
  }
  int ex = sm[t] - s + beg;               // csr position of node 2t of this bucket
  int node0 = (b << BSH) + 2 * t;
  if (node0 < NN)     { offs[node0]     = ex;      deg[node0]     = c0; }
  if (node0 + 1 < NN) { offs[node0 + 1] = ex + c0; deg[node0 + 1] = c1; }
  ncnt[2 * t]     = ex;                   // reuse as cursors
  ncnt[2 * t + 1] = ex + c0;
  __syncthreads();
  for (int e = beg + t; e < beg + cntb; e += 256) {
    unsigned int u = binned[e];
    int p = atomicAdd(&ncnt[u >> 17], 1);
    csr[p] = (int)(u & 0x1FFFFu);
  }
}

// =======================================================================
// Fused: aggregate (gather-sum) + 3x(Linear->BN->ReLU) for one 64-row tile
// Ab rows are wave-private (wave w owns rows w*16..w*16+15) -> barriers
// are only needed around the cooperative Wb staging.
// =======================================================================
__device__ __forceinline__ void gather_tile(const unsigned short* __restrict__ h,
                                            const int* __restrict__ offs,
                                            const int* __restrict__ deg,
                                            const int* __restrict__ csr,
                                            unsigned short* Ab,
                                            int row0, int wave, int lane) {
  int g  = lane >> 4;     // edge stream 0..3
  int sl = lane & 15;     // 16B column chunk
  for (int n = 0; n < 16; n++) {
    int node = row0 + wave * 16 + n;
    bool valid = node < NN;
    float acc[8];
    if (g == 0 && valid) {
      us8 v = *(const us8*)(h + (size_t)node * HF + sl * 8);
      #pragma unroll
      for (int i = 0; i < 8; i++) acc[i] = b2f(v[i]);
    } else {
      #pragma unroll
      for (int i = 0; i < 8; i++) acc[i] = 0.f;
    }
    int beg = 0, dg = 0;
    if (valid) { beg = offs[node]; dg = deg[node]; }
    for (int e = beg + g; e < beg + dg; e += 4) {
      int s = csr[e];
      us8 v = *(const us8*)(h + (size_t)s * HF + sl * 8);
      #pragma unroll
      for (int i = 0; i < 8; i++) acc[i] += b2f(v[i]);
    }
    #pragma unroll
    for (int i = 0; i < 8; i++) {
      acc[i] += __shfl_xor(acc[i], 16, 64);
      acc[i] += __shfl_xor(acc[i], 32, 64);
    }
    if (g == 0) {
      us8 r;
      #pragma unroll
      for (int i = 0; i < 8; i++) r[i] = f2b(acc[i]);
      *(us8*)&Ab[(wave * 16 + n) * AP + sl * 8] = r;
    }
  }
}

__device__ __forceinline__ void mlp3_tile(unsigned short* Ab, unsigned short* Wb,
                                          const unsigned short* __restrict__ wt,
                                          const float* __restrict__ sarr,
                                          const float* __restrict__ tarr,
                                          int layer, int t, int wave, int lane) {
  int m = lane & 15, q = lane >> 4;
  const unsigned short* wbase = wt + layer * 3 * HF * HF;
  for (int sub = 0; sub < 3; sub++) {
    __syncthreads();                        // prev-sub Wb readers done
    const unsigned short* wsub = wbase + sub * HF * HF;
    for (int it = 0; it < 8; it++) {
      int idx = it * 256 + t;               // 128 rows x 16 chunks
      int r = idx >> 4;
      int c = (idx & 15) << 3;
      *(us8*)&Wb[r * AP + c] = *(const us8*)(wsub + r * HF + c);
    }
    __syncthreads();                        // Wb ready

    bf16x8 af[4];
    #pragma unroll
    for (int k0 = 0; k0 < 4; k0++)
      af[k0] = *(const bf16x8*)&Ab[(wave * 16 + m) * AP + k0 * 32 + q * 8];

    f32x4 acc[8];
    #pragma unroll
    for (int nt = 0; nt < 8; nt++) {
      acc[nt] = (f32x4){0.f, 0.f, 0.f, 0.f};
      #pragma unroll
      for (int k0 = 0; k0 < 4; k0++) {
        bf16x8 bf = *(const bf16x8*)&Wb[(nt * 16 + m) * AP + k0 * 32 + q * 8];
        acc[nt] = __builtin_amdgcn_mfma_f32_16x16x32_bf16(af[k0], bf, acc[nt], 0, 0, 0);
      }
    }

    const float* sp = sarr + (layer * 3 + sub) * HF;
    const float* tp = tarr + (layer * 3 + sub) * HF;
    #pragma unroll
    for (int nt = 0; nt < 8; nt++) {
      int c = nt * 16 + m;
      float sc = sp[c], sh = tp[c];
      #pragma unroll
      for (int i = 0; i < 4; i++) {
        int r = wave * 16 + q * 4 + i;     // C/D: col=lane&15, row=(lane>>4)*4+i
        float y = fmaxf(acc[nt][i] * sc + sh, 0.f);
        Ab[r * AP + c] = f2b(y);           // own rows: no barrier needed
      }
    }
  }
}

__global__ __launch_bounds__(256, 3) void agg_mlp(const unsigned short* __restrict__ h,
                                                  unsigned short* __restrict__ out,
                                                  const int* __restrict__ offs,
                                                  const int* __restrict__ deg,
                                                  const int* __restrict__ csr,
                                                  const unsigned short* __restrict__ wt,
                                                  const float* __restrict__ sarr,
                                                  const float* __restrict__ tarr,
                                                  int layer) {
  __shared__ unsigned short Ab[64 * AP];
  __shared__ unsigned short Wb[HF * AP];
  int t = threadIdx.x;
  int lane = t & 63, wave = t >> 6;
  int row0 = blockIdx.x * 64;

  gather_tile(h, offs, deg, csr, Ab, row0, wave, lane);
  mlp3_tile(Ab, Wb, wt, sarr, tarr, layer, t, wave, lane);

  // per-wave coalesced bf16 store of own 16 rows (in-wave LDS write->read)
  for (int it = 0; it < 4; it++) {
    int idx = it * 64 + lane;              // 4 rows x 16 chunks per pass
    int r = wave * 16 + (idx >> 4);
    int c = (idx & 15) << 3;
    int gr = row0 + r;
    if (gr < NN) *(us8*)(out + (size_t)gr * HF + c) = *(const us8*)&Ab[r * AP + c];
  }
}

__global__ __launch_bounds__(256, 3) void agg_mlp_fc(const unsigned short* __restrict__ h,
                                                     float* __restrict__ out,
                                                     const int* __restrict__ offs,
                                                     const int* __restrict__ deg,
                                                     const int* __restrict__ csr,
                                                     const unsigned short* __restrict__ wt,
                                                     const float* __restrict__ sarr,
                                                     const float* __restrict__ tarr,
                                                     const unsigned short* __restrict__ wtf,
                                                     const float* __restrict__ fc_b) {
  __shared__ unsigned short Ab[64 * AP];
  __shared__ unsigned short Wb[HF * AP];
  int t = threadIdx.x;
  int lane = t & 63, wave = t >> 6;
  int row0 = blockIdx.x * 64;

  gather_tile(h, offs, deg, csr, Ab, row0, wave, lane);
  mlp3_tile(Ab, Wb, wt, sarr, tarr, 1, t, wave, lane);

  // ---- FC 128->64 + log_softmax, all in registers ----
  __syncthreads();                         // sub2 Wb readers done
  for (int it = 0; it < 4; it++) {
    int idx = it * 256 + t;                // 64 rows x 16 chunks
    int r = idx >> 4;
    int c = (idx & 15) << 3;
    *(us8*)&Wb[r * AP + c] = *(const us8*)(wtf + r * HF + c);
  }
  __syncthreads();

  int m = lane & 15, q = lane >> 4;
  bf16x8 af[4];
  #pragma unroll
  for (int k0 = 0; k0 < 4; k0++)
    af[k0] = *(const bf16x8*)&Ab[(wave * 16 + m) * AP + k0 * 32 + q * 8];

  f32x4 acc[4];
  #pragma unroll
  for (int nt = 0; nt < 4; nt++) {
    acc[nt] = (f32x4){0.f, 0.f, 0.f, 0.f};
    #pragma unroll
    for (int k0 = 0; k0 < 4; k0++) {
      bf16x8 bf = *(const bf16x8*)&Wb[(nt * 16 + m) * AP + k0 * 32 + q * 8];
      acc[nt] = __builtin_amdgcn_mfma_f32_16x16x32_bf16(af[k0], bf, acc[nt], 0, 0, 0);
    }
  }
  // logits: lane (q,m) holds rows q*4+i (i<4), cols nt*16+m
  float v[4][4];
  #pragma unroll
  for (int nt = 0; nt < 4; nt++) {
    float b = fc_b[nt * 16 + m];
    #pragma unroll
    for (int i = 0; i < 4; i++) v[nt][i] = acc[nt][i] + b;
  }
  float mx[4], sum[4];
  #pragma unroll
  for (int i = 0; i < 4; i++) {
    mx[i] = fmaxf(fmaxf(v[0][i], v[1][i]), fmaxf(v[2][i], v[3][i]));
    mx[i] = fmaxf(mx[i], __shfl_xor(mx[i], 1, 64));
    mx[i] = fmaxf(mx[i], __shfl_xor(mx[i], 2, 64));
    mx[i] = fmaxf(mx[i], __shfl_xor(mx[i], 4, 64));
    mx[i] = fmaxf(mx[i], __shfl_xor(mx[i], 8, 64));
    sum[i] = __expf(v[0][i] - mx[i]) + __expf(v[1][i] - mx[i])
           + __expf(v[2][i] - mx[i]) + __expf(v[3][i] - mx[i]);
    sum[i] += __shfl_xor(sum[i], 1, 64);
    sum[i] += __shfl_xor(sum[i], 2, 64);
    sum[i] += __shfl_xor(sum[i], 4, 64);
    sum[i] += __shfl_xor(sum[i], 8, 64);
    sum[i] = __logf(sum[i]) + mx[i];       // logsumexp
  }
  #pragma unroll
  for (int i = 0; i < 4; i++) {
    int gr = row0 + wave * 16 + q * 4 + i;
    if (gr < NN) {
      #pragma unroll
      for (int nt = 0; nt < 4; nt++)
        out[(size_t)gr * NC + nt * 16 + m] = v[nt][i] - sum[i];
    }
  }
}

// ---------------- launch ----------------
extern "C" void kernel_launch(void* const* d_in, const int* in_sizes, int n_in,
                              void* d_out, int out_size, void* d_ws, size_t ws_size,
                              hipStream_t stream) {
  const float* x      = (const float*)d_in[0];
  const int*   ei     = (const int*)d_in[1];
  const float* conv_w = (const float*)d_in[3];
  const float* conv_b = (const float*)d_in[4];
  const float* bn_g   = (const float*)d_in[5];
  const float* bn_b   = (const float*)d_in[6];
  const float* bn_m   = (const float*)d_in[7];
  const float* bn_v   = (const float*)d_in[8];
  const float* fc_w   = (const float*)d_in[9];
  const float* fc_b   = (const float*)d_in[10];
  float* out = (float*)d_out;

  const int* srcI = ei;        // edge_index[0]
  const int* dstI = ei + NE;   // edge_index[1]

  // workspace layout (~67 MiB)
  unsigned short* Xb   = (unsigned short*)d_ws;          // N*H bf16
  unsigned short* Bbuf = Xb + (size_t)NN * HF;           // N*H bf16
  int* gcur   = (int*)(Bbuf + (size_t)NN * HF);          // 256
  int* offs   = gcur + 256;                              // N+4
  int* deg    = offs + 100004;                           // N+4
  unsigned int* binned = (unsigned int*)(deg + 100004);  // NB*BCAP
  int* csr    = (int*)(binned + (size_t)NB * BCAP);      // NB*BCAP
  unsigned short* wt  = (unsigned short*)(csr + (size_t)NB * BCAP); // 6*128*128 bf16
  unsigned short* wtf = wt + 6 * HF * HF;                // 64*128 bf16
  float* sarr = (float*)(wtf + HF * NC);                 // 6*128
  float* tarr = sarr + 6 * HF;                           // 6*128

  prep_weights<<<384, 256, 0, stream>>>(conv_w, conv_b, bn_g, bn_b, bn_m, bn_v, fc_w,
                                        wt, wtf, sarr, tarr);
  cast_bf16<<<6250, 256, 0, stream>>>(x, Xb);
  init_gcur<<<1, 256, 0, stream>>>(gcur);
  bin_edges<<<196, 256, 0, stream>>>(srcI, dstI, gcur, binned);
  build_csr<<<196, 256, 0, stream>>>(binned, gcur, offs, deg, csr);

  agg_mlp<<<(NN + 63) / 64, 256, 0, stream>>>(Xb, Bbuf, offs, deg, csr, wt, sarr, tarr, 0);
  agg_mlp_fc<<<(NN + 63) / 64, 256, 0, stream>>>(Bbuf, out, offs, deg, csr, wt, sarr, tarr,
                                                 wtf, fc_b);
}

// Round 5
// 384.519 us; speedup vs baseline: 1.4666x; 1.4666x over previous
//
#include <hip/hip_runtime.h>

#define NN 100000
#define NE 1600000
#define HF 128
#define NC 64
#define AP 136      // padded LDS row (bf16 elems): 272B stride, 16B-aligned chunks
#define NB 196      // edge buckets: ceil(100000/512)
#define BSH 9       // 512 nodes per bucket
#define BMASK 511
#define BCAP 9216   // fixed bucket capacity (~12 sigma above mean 8163)

typedef __bf16 bf16x8 __attribute__((ext_vector_type(8)));
typedef float  f32x4  __attribute__((ext_vector_type(4)));
typedef unsigned short us8 __attribute__((ext_vector_type(8)));

__device__ __forceinline__ unsigned short f2b(float x) {
  unsigned int u = __float_as_uint(x);
  u += 0x7FFFu + ((u >> 16) & 1u);   // RNE
  return (unsigned short)(u >> 16);
}
__device__ __forceinline__ float b2f(unsigned short b) {
  return __uint_as_float(((unsigned int)b) << 16);
}

// ---------------- weight prep: bf16 W^T + folded BN affine ----------------
__global__ void prep_weights(const float* __restrict__ conv_w, const float* __restrict__ conv_b,
                             const float* __restrict__ bn_g, const float* __restrict__ bn_b,
                             const float* __restrict__ bn_m, const float* __restrict__ bn_v,
                             const float* __restrict__ fc_w,
                             unsigned short* __restrict__ wt, unsigned short* __restrict__ wtf,
                             float* __restrict__ sarr, float* __restrict__ tarr) {
  int idx = blockIdx.x * 256 + threadIdx.x;
  if (idx < 6 * HF * HF) {
    int ls = idx / (HF * HF);
    int rem = idx - ls * HF * HF;
    int k = rem >> 7;          // input feature
    int n = rem & 127;         // output feature
    wt[(ls * HF + n) * HF + k] = f2b(conv_w[idx]);   // store W^T: [n][k]
  }
  if (idx < HF * NC) {
    int k = idx >> 6;
    int c = idx & 63;
    wtf[c * HF + k] = f2b(fc_w[idx]);                // fc W^T: [c][k]
  }
  if (idx < 6 * HF) {
    float s = bn_g[idx] * rsqrtf(bn_v[idx] + 1e-5f);
    sarr[idx] = s;
    tarr[idx] = (conv_b[idx] - bn_m[idx]) * s + bn_b[idx];  // fold linear bias into BN shift
  }
}

// ---------------- cast x fp32 -> bf16 ----------------
__global__ __launch_bounds__(256) void cast_bf16(const float* __restrict__ x,
                                                 unsigned short* __restrict__ xb) {
  size_t i = (size_t)(blockIdx.x * 256 + threadIdx.x) * 8;
  float4 a = *(const float4*)(x + i);
  float4 b = *(const float4*)(x + i + 4);
  us8 v = { f2b(a.x), f2b(a.y), f2b(a.z), f2b(a.w),
            f2b(b.x), f2b(b.y), f2b(b.z), f2b(b.w) };
  *(us8*)(xb + i) = v;
}

// ---------------- gcur init: fixed-capacity bucket bases ----------------
__global__ void init_gcur(int* __restrict__ gcur) {
  int t = threadIdx.x;
  if (t < NB) gcur[t] = t * BCAP;
}

// ---------------- bin edges into fixed-capacity buckets ----------------
// entry = src (17 bits) | dst_local (9 bits) << 17
__global__ __launch_bounds__(256) void bin_edges(const int* __restrict__ src,
                                                 const int* __restrict__ dst,
                                                 int* __restrict__ gcur,
                                                 unsigned int* __restrict__ binned) {
  __shared__ int hist[NB];
  int t = threadIdx.x;
  if (t < NB) hist[t] = 0;
  __syncthreads();
  int base = blockIdx.x * 8192;
  for (int j = 0; j < 32; j++) {
    int e = base + j * 256 + t;
    if (e < NE) atomicAdd(&hist[dst[e] >> BSH], 1);
  }
  __syncthreads();
  if (t < NB) {                       // reserve contiguous range in this bucket
    int c = hist[t];
    if (c) hist[t] = atomicAdd(&gcur[t], c);
  }
  __syncthreads();
  for (int j = 0; j < 32; j++) {
    int e = base + j * 256 + t;
    if (e < NE) {
      int d = dst[e];
      int b = d >> BSH;
      int p = atomicAdd(&hist[b], 1);
      binned[p] = (unsigned int)src[e] | ((unsigned int)(d & BMASK) << 17);
    }
  }
}

// ---------------- per-bucket CSR build: offs + deg + csr (L2-local scatter) ----
__global__ __launch_bounds__(256) void build_csr(const unsigned int* __restrict__ binned,
                                                 const int* __restrict__ gcur,
                                                 int* __restrict__ offs,
                                                 int* __restrict__ deg,
                                                 int* __restrict__ csr) {
  __shared__ int ncnt[512];
  __shared__ int sm[256];
  int t = threadIdx.x;
  int b = blockIdx.x;
  int beg = b * BCAP;
  int cntb = gcur[b] - beg;
  ncnt[t] = 0; ncnt[t + 256] = 0;
  __syncthreads();
  for (int e = beg + t; e < beg + cntb; e += 256) atomicAdd(&ncnt[binned[e] >> 17], 1);
  __syncthreads();
  int c0 = ncnt[2 * t], c1 = ncnt[2 * t + 1];
  int s = c0 + c1;
  sm[t] = s; __syncthreads();
  for (int off = 1; off < 256; off <<= 1) {
    int u = (t >= off) ? sm[t - off] : 0;
    __syncthreads();
    sm[t] += u;
    __syncthreads();
  }
  int ex = sm[t] - s + beg;               // csr position of node 2t of this bucket
  int node0 = (b << BSH) + 2 * t;
  if (node0 < NN)     { offs[node0]     = ex;      deg[node0]     = c0; }
  if (node0 + 1 < NN) { offs[node0 + 1] = ex + c0; deg[node0 + 1] = c1; }
  ncnt[2 * t]     = ex;                   // reuse as cursors
  ncnt[2 * t + 1] = ex + c0;
  __syncthreads();
  for (int e = beg + t; e < beg + cntb; e += 256) {
    unsigned int u = binned[e];
    int p = atomicAdd(&ncnt[u >> 17], 1);
    csr[p] = (int)(u & 0x1FFFFu);
  }
}

// ---------------- aggregation: hsum[i] = h[i] + sum_{e->i} h[src_e]  (bf16) ----
// Standalone, LDS-free, VGPR-light -> high occupancy for latency hiding.
__global__ __launch_bounds__(256) void aggregate(const unsigned short* __restrict__ h,
                                                 const int* __restrict__ offs,
                                                 const int* __restrict__ deg,
                                                 const int* __restrict__ csr,
                                                 unsigned short* __restrict__ out) {
  int wave = threadIdx.x >> 6;
  int lane = threadIdx.x & 63;
  int node = blockIdx.x * 4 + wave;
  if (node >= NN) return;
  int g  = lane >> 4;     // edge stream 0..3
  int sl = lane & 15;     // 16B column chunk
  int beg = offs[node];
  int dg  = deg[node];

  float acc[8];
  if (g == 0) {           // self contribution counted once
    us8 v = *(const us8*)(h + (size_t)node * HF + sl * 8);
    #pragma unroll
    for (int i = 0; i < 8; i++) acc[i] = b2f(v[i]);
  } else {
    #pragma unroll
    for (int i = 0; i < 8; i++) acc[i] = 0.f;
  }

  for (int e = beg + g; e < beg + dg; e += 4) {
    int s = csr[e];
    us8 v = *(const us8*)(h + (size_t)s * HF + sl * 8);
    #pragma unroll
    for (int i = 0; i < 8; i++) acc[i] += b2f(v[i]);
  }

  #pragma unroll
  for (int i = 0; i < 8; i++) {
    acc[i] += __shfl_xor(acc[i], 16, 64);
    acc[i] += __shfl_xor(acc[i], 32, 64);
  }
  if (g == 0) {
    us8 r;
    #pragma unroll
    for (int i = 0; i < 8; i++) r[i] = f2b(acc[i]);
    *(us8*)(out + (size_t)node * HF + sl * 8) = r;
  }
}

// ---------------- shared MLP tile body: 3x (Linear->BN->ReLU) in LDS ----------
__device__ __forceinline__ void stage_tile(const unsigned short* __restrict__ in,
                                           unsigned short* Ab, int row0, int t) {
  for (int it = 0; it < 4; it++) {
    int idx = it * 256 + t;          // 64 rows x 16 chunks
    int r = idx >> 4;
    int c = (idx & 15) << 3;
    int gr = row0 + r;
    us8 v = (us8)(0);
    if (gr < NN) v = *(const us8*)(in + (size_t)gr * HF + c);
    *(us8*)&Ab[r * AP + c] = v;
  }
}

__device__ __forceinline__ void mlp3_tile(unsigned short* Ab, unsigned short* Wb,
                                          const unsigned short* __restrict__ wt,
                                          const float* __restrict__ sarr,
                                          const float* __restrict__ tarr,
                                          int layer, int t, int wave, int lane) {
  int m = lane & 15, q = lane >> 4;
  const unsigned short* wbase = wt + layer * 3 * HF * HF;
  for (int sub = 0; sub < 3; sub++) {
    __syncthreads();                        // Ab ready / prev Wb readers done
    const unsigned short* wsub = wbase + sub * HF * HF;
    for (int it = 0; it < 8; it++) {
      int idx = it * 256 + t;               // 128 rows x 16 chunks
      int r = idx >> 4;
      int c = (idx & 15) << 3;
      *(us8*)&Wb[r * AP + c] = *(const us8*)(wsub + r * HF + c);
    }
    __syncthreads();                        // Wb ready

    bf16x8 af[4];
    #pragma unroll
    for (int k0 = 0; k0 < 4; k0++)
      af[k0] = *(const bf16x8*)&Ab[(wave * 16 + m) * AP + k0 * 32 + q * 8];

    f32x4 acc[8];
    #pragma unroll
    for (int nt = 0; nt < 8; nt++) {
      acc[nt] = (f32x4){0.f, 0.f, 0.f, 0.f};
      #pragma unroll
      for (int k0 = 0; k0 < 4; k0++) {
        bf16x8 bf = *(const bf16x8*)&Wb[(nt * 16 + m) * AP + k0 * 32 + q * 8];
        acc[nt] = __builtin_amdgcn_mfma_f32_16x16x32_bf16(af[k0], bf, acc[nt], 0, 0, 0);
      }
    }

    const float* sp = sarr + (layer * 3 + sub) * HF;
    const float* tp = tarr + (layer * 3 + sub) * HF;
    #pragma unroll
    for (int nt = 0; nt < 8; nt++) {
      int c = nt * 16 + m;
      float sc = sp[c], sh = tp[c];
      #pragma unroll
      for (int i = 0; i < 4; i++) {
        int r = wave * 16 + q * 4 + i;     // C/D: col=lane&15, row=(lane>>4)*4+i
        float y = fmaxf(acc[nt][i] * sc + sh, 0.f);
        Ab[r * AP + c] = f2b(y);           // own rows: no barrier needed
      }
    }
  }
}

// ---------------- layer-0 MLP: bf16 in -> bf16 out ----------------
__global__ __launch_bounds__(256) void mlp3(const unsigned short* __restrict__ in,
                                            unsigned short* __restrict__ out,
                                            const unsigned short* __restrict__ wt,
                                            const float* __restrict__ sarr,
                                            const float* __restrict__ tarr) {
  __shared__ unsigned short Ab[64 * AP];
  __shared__ unsigned short Wb[HF * AP];
  int t = threadIdx.x;
  int lane = t & 63, wave = t >> 6;
  int row0 = blockIdx.x * 64;

  stage_tile(in, Ab, row0, t);
  mlp3_tile(Ab, Wb, wt, sarr, tarr, 0, t, wave, lane);

  __syncthreads();
  for (int it = 0; it < 4; it++) {
    int idx = it * 256 + t;
    int r = idx >> 4;
    int c = (idx & 15) << 3;
    int gr = row0 + r;
    if (gr < NN) *(us8*)(out + (size_t)gr * HF + c) = *(const us8*)&Ab[r * AP + c];
  }
}

// ---------------- layer-1 MLP + FC(128->64) + log_softmax ----------------
__global__ __launch_bounds__(256) void mlp3fc(const unsigned short* __restrict__ in,
                                              float* __restrict__ out,
                                              const unsigned short* __restrict__ wt,
                                              const float* __restrict__ sarr,
                                              const float* __restrict__ tarr,
                                              const unsigned short* __restrict__ wtf,
                                              const float* __restrict__ fc_b) {
  __shared__ unsigned short Ab[64 * AP];
  __shared__ unsigned short Wb[HF * AP];
  int t = threadIdx.x;
  int lane = t & 63, wave = t >> 6;
  int row0 = blockIdx.x * 64;

  stage_tile(in, Ab, row0, t);
  mlp3_tile(Ab, Wb, wt, sarr, tarr, 1, t, wave, lane);

  // ---- FC + log_softmax, all in registers ----
  __syncthreads();                         // sub2 Wb readers done
  for (int it = 0; it < 4; it++) {
    int idx = it * 256 + t;                // 64 rows x 16 chunks
    int r = idx >> 4;
    int c = (idx & 15) << 3;
    *(us8*)&Wb[r * AP + c] = *(const us8*)(wtf + r * HF + c);
  }
  __syncthreads();

  int m = lane & 15, q = lane >> 4;
  bf16x8 af[4];
  #pragma unroll
  for (int k0 = 0; k0 < 4; k0++)
    af[k0] = *(const bf16x8*)&Ab[(wave * 16 + m) * AP + k0 * 32 + q * 8];

  f32x4 acc[4];
  #pragma unroll
  for (int nt = 0; nt < 4; nt++) {
    acc[nt] = (f32x4){0.f, 0.f, 0.f, 0.f};
    #pragma unroll
    for (int k0 = 0; k0 < 4; k0++) {
      bf16x8 bf = *(const bf16x8*)&Wb[(nt * 16 + m) * AP + k0 * 32 + q * 8];
      acc[nt] = __builtin_amdgcn_mfma_f32_16x16x32_bf16(af[k0], bf, acc[nt], 0, 0, 0);
    }
  }
  // logits: lane (q,m) holds rows q*4+i (i<4), cols nt*16+m
  float v[4][4];
  #pragma unroll
  for (int nt = 0; nt < 4; nt++) {
    float b = fc_b[nt * 16 + m];
    #pragma unroll
    for (int i = 0; i < 4; i++) v[nt][i] = acc[nt][i] + b;
  }
  float mx[4], sum[4];
  #pragma unroll
  for (int i = 0; i < 4; i++) {
    mx[i] = fmaxf(fmaxf(v[0][i], v[1][i]), fmaxf(v[2][i], v[3][i]));
    mx[i] = fmaxf(mx[i], __shfl_xor(mx[i], 1, 64));
    mx[i] = fmaxf(mx[i], __shfl_xor(mx[i], 2, 64));
    mx[i] = fmaxf(mx[i], __shfl_xor(mx[i], 4, 64));
    mx[i] = fmaxf(mx[i], __shfl_xor(mx[i], 8, 64));
    sum[i] = __expf(v[0][i] - mx[i]) + __expf(v[1][i] - mx[i])
           + __expf(v[2][i] - mx[i]) + __expf(v[3][i] - mx[i]);
    sum[i] += __shfl_xor(sum[i], 1, 64);
    sum[i] += __shfl_xor(sum[i], 2, 64);
    sum[i] += __shfl_xor(sum[i], 4, 64);
    sum[i] += __shfl_xor(sum[i], 8, 64);
    sum[i] = __logf(sum[i]) + mx[i];       // logsumexp
  }
  #pragma unroll
  for (int i = 0; i < 4; i++) {
    int gr = row0 + wave * 16 + q * 4 + i;
    if (gr < NN) {
      #pragma unroll
      for (int nt = 0; nt < 4; nt++)
        out[(size_t)gr * NC + nt * 16 + m] = v[nt][i] - sum[i];
    }
  }
}

// ---------------- launch ----------------
extern "C" void kernel_launch(void* const* d_in, const int* in_sizes, int n_in,
                              void* d_out, int out_size, void* d_ws, size_t ws_size,
                              hipStream_t stream) {
  const float* x      = (const float*)d_in[0];
  const int*   ei     = (const int*)d_in[1];
  const float* conv_w = (const float*)d_in[3];
  const float* conv_b = (const float*)d_in[4];
  const float* bn_g   = (const float*)d_in[5];
  const float* bn_b   = (const float*)d_in[6];
  const float* bn_m   = (const float*)d_in[7];
  const float* bn_v   = (const float*)d_in[8];
  const float* fc_w   = (const float*)d_in[9];
  const float* fc_b   = (const float*)d_in[10];
  float* out = (float*)d_out;

  const int* srcI = ei;        // edge_index[0]
  const int* dstI = ei + NE;   // edge_index[1]

  // workspace layout (~92 MiB)
  unsigned short* Xb   = (unsigned short*)d_ws;          // N*H bf16
  unsigned short* Abuf = Xb + (size_t)NN * HF;           // N*H bf16
  unsigned short* Bbuf = Abuf + (size_t)NN * HF;         // N*H bf16
  int* gcur   = (int*)(Bbuf + (size_t)NN * HF);          // 256
  int* offs   = gcur + 256;                              // N+4
  int* deg    = offs + 100004;                           // N+4
  unsigned int* binned = (unsigned int*)(deg + 100004);  // NB*BCAP
  int* csr    = (int*)(binned + (size_t)NB * BCAP);      // NB*BCAP
  unsigned short* wt  = (unsigned short*)(csr + (size_t)NB * BCAP); // 6*128*128 bf16
  unsigned short* wtf = wt + 6 * HF * HF;                // 64*128 bf16
  float* sarr = (float*)(wtf + HF * NC);                 // 6*128
  float* tarr = sarr + 6 * HF;                           // 6*128

  prep_weights<<<384, 256, 0, stream>>>(conv_w, conv_b, bn_g, bn_b, bn_m, bn_v, fc_w,
                                        wt, wtf, sarr, tarr);
  cast_bf16<<<6250, 256, 0, stream>>>(x, Xb);
  init_gcur<<<1, 256, 0, stream>>>(gcur);
  bin_edges<<<196, 256, 0, stream>>>(srcI, dstI, gcur, binned);
  build_csr<<<196, 256, 0, stream>>>(binned, gcur, offs, deg, csr);

  aggregate<<<NN / 4, 256, 0, stream>>>(Xb, offs, deg, csr, Abuf);
  mlp3<<<(NN + 63) / 64, 256, 0, stream>>>(Abuf, Bbuf, wt, sarr, tarr);
  aggregate<<<NN / 4, 256, 0, stream>>>(Bbuf, offs, deg, csr, Abuf);
  mlp3fc<<<(NN + 63) / 64, 256, 0, stream>>>(Abuf, out, wt, sarr, tarr, wtf, fc_b);
}

// Round 6
// 383.335 us; speedup vs baseline: 1.4711x; 1.0031x over previous
//
#include <hip/hip_runtime.h>

#define NN 100000
#define NE 1600000
#define HF 128
#define NC 64
#define AP 136      // padded LDS row (bf16 elems): 272B stride, 16B-aligned chunks
#define NB 196      // edge buckets: ceil(100000/512)
#define BSH 9       // 512 nodes per bucket
#define BMASK 511
#define BCAP 9216   // fixed bucket capacity (~12 sigma above mean 8163)

typedef __bf16 bf16x8 __attribute__((ext_vector_type(8)));
typedef float  f32x4  __attribute__((ext_vector_type(4)));
typedef unsigned short us8 __attribute__((ext_vector_type(8)));

__device__ __forceinline__ unsigned short f2b(float x) {
  unsigned int u = __float_as_uint(x);
  u += 0x7FFFu + ((u >> 16) & 1u);   // RNE
  return (unsigned short)(u >> 16);
}
__device__ __forceinline__ float b2f(unsigned short b) {
  return __uint_as_float(((unsigned int)b) << 16);
}

// ---------------- weight prep: bf16 fragment-swizzled W^T + folded BN affine ----
// wt layout (ushort):  ((((ls)*4 + k0)*8 + nt)*64 + q*16 + m)*8 + j
//   = B-fragment for lane (q,m): W^T[n=nt*16+m][k=k0*32+q*8+j]   (ls = layer*3+sub)
// wtf layout (ushort): (((k0)*4 + nt)*64 + q*16 + m)*8 + j  <- fc W^T fragments
__global__ void prep_weights(const float* __restrict__ conv_w, const float* __restrict__ conv_b,
                             const float* __restrict__ bn_g, const float* __restrict__ bn_b,
                             const float* __restrict__ bn_m, const float* __restrict__ bn_v,
                             const float* __restrict__ fc_w,
                             unsigned short* __restrict__ wt, unsigned short* __restrict__ wtf,
                             float* __restrict__ sarr, float* __restrict__ tarr) {
  int idx = blockIdx.x * 256 + threadIdx.x;
  if (idx < 6 * HF * HF) {
    int j  = idx & 7;
    int m  = (idx >> 3) & 15;
    int q  = (idx >> 7) & 3;
    int nt = (idx >> 9) & 7;
    int k0 = (idx >> 12) & 3;
    int ls = idx >> 14;                 // 0..5
    int k = k0 * 32 + q * 8 + j;
    int n = nt * 16 + m;
    wt[idx] = f2b(conv_w[(ls * HF + k) * HF + n]);
  }
  if (idx < HF * NC) {
    int j  = idx & 7;
    int m  = (idx >> 3) & 15;
    int q  = (idx >> 7) & 3;
    int nt = (idx >> 9) & 3;
    int k0 = idx >> 11;                 // 0..3
    int k = k0 * 32 + q * 8 + j;
    int c = nt * 16 + m;
    wtf[idx] = f2b(fc_w[k * NC + c]);
  }
  if (idx < 6 * HF) {
    float s = bn_g[idx] * rsqrtf(bn_v[idx] + 1e-5f);
    sarr[idx] = s;
    tarr[idx] = (conv_b[idx] - bn_m[idx]) * s + bn_b[idx];  // fold linear bias into BN shift
  }
}

// ---------------- cast x fp32 -> bf16 ----------------
__global__ __launch_bounds__(256) void cast_bf16(const float* __restrict__ x,
                                                 unsigned short* __restrict__ xb) {
  size_t i = (size_t)(blockIdx.x * 256 + threadIdx.x) * 8;
  float4 a = *(const float4*)(x + i);
  float4 b = *(const float4*)(x + i + 4);
  us8 v = { f2b(a.x), f2b(a.y), f2b(a.z), f2b(a.w),
            f2b(b.x), f2b(b.y), f2b(b.z), f2b(b.w) };
  *(us8*)(xb + i) = v;
}

// ---------------- gcur init: fixed-capacity bucket bases ----------------
__global__ void init_gcur(int* __restrict__ gcur) {
  int t = threadIdx.x;
  if (t < NB) gcur[t] = t * BCAP;
}

// ---------------- bin edges into fixed-capacity buckets ----------------
// entry = src (17 bits) | dst_local (9 bits) << 17
__global__ __launch_bounds__(256) void bin_edges(const int* __restrict__ src,
                                                 const int* __restrict__ dst,
                                                 int* __restrict__ gcur,
                                                 unsigned int* __restrict__ binned) {
  __shared__ int hist[NB];
  int t = threadIdx.x;
  if (t < NB) hist[t] = 0;
  __syncthreads();
  int base = blockIdx.x * 8192;
  for (int j = 0; j < 32; j++) {
    int e = base + j * 256 + t;
    if (e < NE) atomicAdd(&hist[dst[e] >> BSH], 1);
  }
  __syncthreads();
  if (t < NB) {                       // reserve contiguous range in this bucket
    int c = hist[t];
    if (c) hist[t] = atomicAdd(&gcur[t], c);
  }
  __syncthreads();
  for (int j = 0; j < 32; j++) {
    int e = base + j * 256 + t;
    if (e < NE) {
      int d = dst[e];
      int b = d >> BSH;
      int p = atomicAdd(&hist[b], 1);
      binned[p] = (unsigned int)src[e] | ((unsigned int)(d & BMASK) << 17);
    }
  }
}

// ---------------- per-bucket CSR build: offs + deg + csr (L2-local scatter) ----
__global__ __launch_bounds__(256) void build_csr(const unsigned int* __restrict__ binned,
                                                 const int* __restrict__ gcur,
                                                 int* __restrict__ offs,
                                                 int* __restrict__ deg,
                                                 int* __restrict__ csr) {
  __shared__ int ncnt[512];
  __shared__ int sm[256];
  int t = threadIdx.x;
  int b = blockIdx.x;
  int beg = b * BCAP;
  int cntb = gcur[b] - beg;
  ncnt[t] = 0; ncnt[t + 256] = 0;
  __syncthreads();
  for (int e = beg + t; e < beg + cntb; e += 256) atomicAdd(&ncnt[binned[e] >> 17], 1);
  __syncthreads();
  int c0 = ncnt[2 * t], c1 = ncnt[2 * t + 1];
  int s = c0 + c1;
  sm[t] = s; __syncthreads();
  for (int off = 1; off < 256; off <<= 1) {
    int u = (t >= off) ? sm[t - off] : 0;
    __syncthreads();
    sm[t] += u;
    __syncthreads();
  }
  int ex = sm[t] - s + beg;               // csr position of node 2t of this bucket
  int node0 = (b << BSH) + 2 * t;
  if (node0 < NN)     { offs[node0]     = ex;      deg[node0]     = c0; }
  if (node0 + 1 < NN) { offs[node0 + 1] = ex + c0; deg[node0 + 1] = c1; }
  ncnt[2 * t]     = ex;                   // reuse as cursors
  ncnt[2 * t + 1] = ex + c0;
  __syncthreads();
  for (int e = beg + t; e < beg + cntb; e += 256) {
    unsigned int u = binned[e];
    int p = atomicAdd(&ncnt[u >> 17], 1);
    csr[p] = (int)(u & 0x1FFFFu);
  }
}

// ---------------- aggregation: hsum[i] = h[i] + sum_{e->i} h[src_e]  (bf16) ----
__global__ __launch_bounds__(256) void aggregate(const unsigned short* __restrict__ h,
                                                 const int* __restrict__ offs,
                                                 const int* __restrict__ deg,
                                                 const int* __restrict__ csr,
                                                 unsigned short* __restrict__ out) {
  int wave = threadIdx.x >> 6;
  int lane = threadIdx.x & 63;
  int node = blockIdx.x * 4 + wave;
  if (node >= NN) return;
  int g  = lane >> 4;     // edge stream 0..3
  int sl = lane & 15;     // 16B column chunk
  int beg = offs[node];
  int dg  = deg[node];

  float acc[8];
  if (g == 0) {           // self contribution counted once
    us8 v = *(const us8*)(h + (size_t)node * HF + sl * 8);
    #pragma unroll
    for (int i = 0; i < 8; i++) acc[i] = b2f(v[i]);
  } else {
    #pragma unroll
    for (int i = 0; i < 8; i++) acc[i] = 0.f;
  }

  for (int e = beg + g; e < beg + dg; e += 4) {
    int s = csr[e];
    us8 v = *(const us8*)(h + (size_t)s * HF + sl * 8);
    #pragma unroll
    for (int i = 0; i < 8; i++) acc[i] += b2f(v[i]);
  }

  #pragma unroll
  for (int i = 0; i < 8; i++) {
    acc[i] += __shfl_xor(acc[i], 16, 64);
    acc[i] += __shfl_xor(acc[i], 32, 64);
  }
  if (g == 0) {
    us8 r;
    #pragma unroll
    for (int i = 0; i < 8; i++) r[i] = f2b(acc[i]);
    *(us8*)(out + (size_t)node * HF + sl * 8) = r;
  }
}

// =======================================================================
// Barrier-free MLP: weights loaded directly from global (fragment-swizzled,
// L1/L2-resident); activations wave-private (global -> regs -> LDS own rows).
// =======================================================================
// Runs subs 0..2 of one layer over the wave's 16 rows; leaves final bf16
// activations in Ab (own rows) and fragments in af.
__device__ __forceinline__ void mlp3_body(const unsigned short* __restrict__ in,
                                          unsigned short* Ab,
                                          const unsigned short* __restrict__ wt,
                                          const float* __restrict__ sarr,
                                          const float* __restrict__ tarr,
                                          int layer, int row0, int wave, int lane,
                                          bf16x8 af[4]) {
  int m = lane & 15, q = lane >> 4;
  int node = row0 + wave * 16 + m;
  int nclamp = (node < NN) ? node : 0;        // OOB rows compute garbage, never stored
  #pragma unroll
  for (int k0 = 0; k0 < 4; k0++)
    af[k0] = *(const bf16x8*)(in + (size_t)nclamp * HF + k0 * 32 + q * 8);

  const unsigned short* wbase = wt + layer * 3 * 16384;   // 16384 ushorts per sub
  #pragma unroll
  for (int sub = 0; sub < 3; sub++) {
    const unsigned short* wsub = wbase + sub * 16384;
    f32x4 acc[8];
    #pragma unroll
    for (int nt = 0; nt < 8; nt++) {
      acc[nt] = (f32x4){0.f, 0.f, 0.f, 0.f};
      #pragma unroll
      for (int k0 = 0; k0 < 4; k0++) {
        bf16x8 bf = *(const bf16x8*)(wsub + ((k0 * 8 + nt) * 64 + lane) * 8);
        acc[nt] = __builtin_amdgcn_mfma_f32_16x16x32_bf16(af[k0], bf, acc[nt], 0, 0, 0);
      }
    }
    const float* sp = sarr + (layer * 3 + sub) * HF;
    const float* tp = tarr + (layer * 3 + sub) * HF;
    #pragma unroll
    for (int nt = 0; nt < 8; nt++) {
      int c = nt * 16 + m;
      float sc = sp[c], sh = tp[c];
      #pragma unroll
      for (int i = 0; i < 4; i++) {
        int r = wave * 16 + q * 4 + i;     // C/D: col=lane&15, row=(lane>>4)*4+i
        float y = fmaxf(acc[nt][i] * sc + sh, 0.f);
        Ab[r * AP + c] = f2b(y);           // own rows: no barrier
      }
    }
    #pragma unroll
    for (int k0 = 0; k0 < 4; k0++)         // reload fragments (wave-local LDS RAW)
      af[k0] = *(const bf16x8*)&Ab[(wave * 16 + m) * AP + k0 * 32 + q * 8];
  }
}

// ---------------- layer-0 MLP: bf16 in -> bf16 out ----------------
__global__ __launch_bounds__(256) void mlp3(const unsigned short* __restrict__ in,
                                            unsigned short* __restrict__ out,
                                            const unsigned short* __restrict__ wt,
                                            const float* __restrict__ sarr,
                                            const float* __restrict__ tarr) {
  __shared__ unsigned short Ab[64 * AP];
  int t = threadIdx.x;
  int lane = t & 63, wave = t >> 6;
  int row0 = blockIdx.x * 64;
  bf16x8 af[4];
  mlp3_body(in, Ab, wt, sarr, tarr, 0, row0, wave, lane, af);

  // wave-local coalesced bf16 store of own 16 rows
  for (int it = 0; it < 4; it++) {
    int idx = it * 64 + lane;              // 4 rows x 16 chunks per pass
    int r = wave * 16 + (idx >> 4);
    int c = (idx & 15) << 3;
    int gr = row0 + r;
    if (gr < NN) *(us8*)(out + (size_t)gr * HF + c) = *(const us8*)&Ab[r * AP + c];
  }
}

// ---------------- layer-1 MLP + FC(128->64) + log_softmax ----------------
__global__ __launch_bounds__(256) void mlp3fc(const unsigned short* __restrict__ in,
                                              float* __restrict__ out,
                                              const unsigned short* __restrict__ wt,
                                              const float* __restrict__ sarr,
                                              const float* __restrict__ tarr,
                                              const unsigned short* __restrict__ wtf,
                                              const float* __restrict__ fc_b) {
  __shared__ unsigned short Ab[64 * AP];
  int t = threadIdx.x;
  int lane = t & 63, wave = t >> 6;
  int row0 = blockIdx.x * 64;
  int m = lane & 15, q = lane >> 4;
  bf16x8 af[4];
  mlp3_body(in, Ab, wt, sarr, tarr, 1, row0, wave, lane, af);

  // ---- FC 128->64 + log_softmax, all in registers ----
  f32x4 acc[4];
  #pragma unroll
  for (int nt = 0; nt < 4; nt++) {
    acc[nt] = (f32x4){0.f, 0.f, 0.f, 0.f};
    #pragma unroll
    for (int k0 = 0; k0 < 4; k0++) {
      bf16x8 bf = *(const bf16x8*)(wtf + ((k0 * 4 + nt) * 64 + lane) * 8);
      acc[nt] = __builtin_amdgcn_mfma_f32_16x16x32_bf16(af[k0], bf, acc[nt], 0, 0, 0);
    }
  }
  // logits: lane (q,m) holds rows q*4+i (i<4), cols nt*16+m
  float v[4][4];
  #pragma unroll
  for (int nt = 0; nt < 4; nt++) {
    float b = fc_b[nt * 16 + m];
    #pragma unroll
    for (int i = 0; i < 4; i++) v[nt][i] = acc[nt][i] + b;
  }
  float mx[4], sum[4];
  #pragma unroll
  for (int i = 0; i < 4; i++) {
    mx[i] = fmaxf(fmaxf(v[0][i], v[1][i]), fmaxf(v[2][i], v[3][i]));
    mx[i] = fmaxf(mx[i], __shfl_xor(mx[i], 1, 64));
    mx[i] = fmaxf(mx[i], __shfl_xor(mx[i], 2, 64));
    mx[i] = fmaxf(mx[i], __shfl_xor(mx[i], 4, 64));
    mx[i] = fmaxf(mx[i], __shfl_xor(mx[i], 8, 64));
    sum[i] = __expf(v[0][i] - mx[i]) + __expf(v[1][i] - mx[i])
           + __expf(v[2][i] - mx[i]) + __expf(v[3][i] - mx[i]);
    sum[i] += __shfl_xor(sum[i], 1, 64);
    sum[i] += __shfl_xor(sum[i], 2, 64);
    sum[i] += __shfl_xor(sum[i], 4, 64);
    sum[i] += __shfl_xor(sum[i], 8, 64);
    sum[i] = __logf(sum[i]) + mx[i];       // logsumexp
  }
  #pragma unroll
  for (int i = 0; i < 4; i++) {
    int gr = row0 + wave * 16 + q * 4 + i;
    if (gr < NN) {
      #pragma unroll
      for (int nt = 0; nt < 4; nt++)
        out[(size_t)gr * NC + nt * 16 + m] = v[nt][i] - sum[i];
    }
  }
}

// ---------------- launch ----------------
extern "C" void kernel_launch(void* const* d_in, const int* in_sizes, int n_in,
                              void* d_out, int out_size, void* d_ws, size_t ws_size,
                              hipStream_t stream) {
  const float* x      = (const float*)d_in[0];
  const int*   ei     = (const int*)d_in[1];
  const float* conv_w = (const float*)d_in[3];
  const float* conv_b = (const float*)d_in[4];
  const float* bn_g   = (const float*)d_in[5];
  const float* bn_b   = (const float*)d_in[6];
  const float* bn_m   = (const float*)d_in[7];
  const float* bn_v   = (const float*)d_in[8];
  const float* fc_w   = (const float*)d_in[9];
  const float* fc_b   = (const float*)d_in[10];
  float* out = (float*)d_out;

  const int* srcI = ei;        // edge_index[0]
  const int* dstI = ei + NE;   // edge_index[1]

  // workspace layout (~92 MiB)
  unsigned short* Xb   = (unsigned short*)d_ws;          // N*H bf16
  unsigned short* Abuf = Xb + (size_t)NN * HF;           // N*H bf16
  unsigned short* Bbuf = Abuf + (size_t)NN * HF;         // N*H bf16
  int* gcur   = (int*)(Bbuf + (size_t)NN * HF);          // 256
  int* offs   = gcur + 256;                              // N+4
  int* deg    = offs + 100004;                           // N+4
  unsigned int* binned = (unsigned int*)(deg + 100004);  // NB*BCAP
  int* csr    = (int*)(binned + (size_t)NB * BCAP);      // NB*BCAP
  unsigned short* wt  = (unsigned short*)(csr + (size_t)NB * BCAP); // 6*16384 bf16 (swizzled)
  unsigned short* wtf = wt + 6 * HF * HF;                // 64*128 bf16 (swizzled)
  float* sarr = (float*)(wtf + HF * NC);                 // 6*128
  float* tarr = sarr + 6 * HF;                           // 6*128

  prep_weights<<<384, 256, 0, stream>>>(conv_w, conv_b, bn_g, bn_b, bn_m, bn_v, fc_w,
                                        wt, wtf, sarr, tarr);
  cast_bf16<<<6250, 256, 0, stream>>>(x, Xb);
  init_gcur<<<1, 256, 0, stream>>>(gcur);
  bin_edges<<<196, 256, 0, stream>>>(srcI, dstI, gcur, binned);
  build_csr<<<196, 256, 0, stream>>>(binned, gcur, offs, deg, csr);

  aggregate<<<NN / 4, 256, 0, stream>>>(Xb, offs, deg, csr, Abuf);
  mlp3<<<(NN + 63) / 64, 256, 0, stream>>>(Abuf, Bbuf, wt, sarr, tarr);
  aggregate<<<NN / 4, 256, 0, stream>>>(Bbuf, offs, deg, csr, Abuf);
  mlp3fc<<<(NN + 63) / 64, 256, 0, stream>>>(Abuf, out, wt, sarr, tarr, wtf, fc_b);
}

// Round 7
// 343.194 us; speedup vs baseline: 1.6432x; 1.1170x over previous
//
#include <hip/hip_runtime.h>

#define NN 100000
#define NE 1600000
#define HF 128
#define NC 64
#define AP 136      // padded LDS row (bf16 elems): 272B stride, 16B-aligned chunks
#define NB 391      // edge buckets: ceil(100000/256)
#define BSH 8       // 256 nodes per bucket
#define BMASK 255
#define BCAP 4608   // fixed bucket capacity (mean 4096 + 8 sigma)

typedef __bf16 bf16x8 __attribute__((ext_vector_type(8)));
typedef float  f32x4  __attribute__((ext_vector_type(4)));
typedef unsigned short us8 __attribute__((ext_vector_type(8)));

__device__ __forceinline__ unsigned short f2b(float x) {
  unsigned int u = __float_as_uint(x);
  u += 0x7FFFu + ((u >> 16) & 1u);   // RNE
  return (unsigned short)(u >> 16);
}
__device__ __forceinline__ float b2f(unsigned short b) {
  return __uint_as_float(((unsigned int)b) << 16);
}

// ---------------- prologue: cast x->bf16, swizzle weights, init gcur ----------
// wt layout (ushort):  ((((ls)*4 + k0)*8 + nt)*64 + q*16 + m)*8 + j
//   = B-fragment for lane (q,m): W^T[n=nt*16+m][k=k0*32+q*8+j]   (ls = layer*3+sub)
// wtf layout (ushort): (((k0)*4 + nt)*64 + q*16 + m)*8 + j  <- fc W^T fragments
__global__ __launch_bounds__(256) void prologue(const float* __restrict__ x,
                                                unsigned short* __restrict__ xb,
                                                const float* __restrict__ conv_w,
                                                const float* __restrict__ conv_b,
                                                const float* __restrict__ bn_g,
                                                const float* __restrict__ bn_b,
                                                const float* __restrict__ bn_m,
                                                const float* __restrict__ bn_v,
                                                const float* __restrict__ fc_w,
                                                unsigned short* __restrict__ wt,
                                                unsigned short* __restrict__ wtf,
                                                float* __restrict__ sarr,
                                                float* __restrict__ tarr,
                                                int* __restrict__ gcur) {
  int idx = blockIdx.x * 256 + threadIdx.x;       // grid 6250*256 = 1.6M
  // cast: 12.8M floats, 8 per thread
  {
    size_t i = (size_t)idx * 8;
    float4 a = *(const float4*)(x + i);
    float4 b = *(const float4*)(x + i + 4);
    us8 v = { f2b(a.x), f2b(a.y), f2b(a.z), f2b(a.w),
              f2b(b.x), f2b(b.y), f2b(b.z), f2b(b.w) };
    *(us8*)(xb + i) = v;
  }
  if (idx < 6 * HF * HF) {
    int j  = idx & 7;
    int m  = (idx >> 3) & 15;
    int q  = (idx >> 7) & 3;
    int nt = (idx >> 9) & 7;
    int k0 = (idx >> 12) & 3;
    int ls = idx >> 14;                 // 0..5
    int k = k0 * 32 + q * 8 + j;
    int n = nt * 16 + m;
    wt[idx] = f2b(conv_w[(ls * HF + k) * HF + n]);
  }
  if (idx < HF * NC) {
    int j  = idx & 7;
    int m  = (idx >> 3) & 15;
    int q  = (idx >> 7) & 3;
    int nt = (idx >> 9) & 3;
    int k0 = idx >> 11;                 // 0..3
    int k = k0 * 32 + q * 8 + j;
    int c = nt * 16 + m;
    wtf[idx] = f2b(fc_w[k * NC + c]);
  }
  if (idx < 6 * HF) {
    float s = bn_g[idx] * rsqrtf(bn_v[idx] + 1e-5f);
    sarr[idx] = s;
    tarr[idx] = (conv_b[idx] - bn_m[idx]) * s + bn_b[idx];  // fold linear bias into BN shift
  }
  if (idx < NB) gcur[idx] = idx * BCAP;
}

// ---------------- bin edges into fixed-capacity buckets (single read pass) ----
// entry = src (17 bits) | dst_local (8 bits) << 17
__global__ __launch_bounds__(512) void bin_edges(const int* __restrict__ src,
                                                 const int* __restrict__ dst,
                                                 int* __restrict__ gcur,
                                                 unsigned int* __restrict__ binned) {
  __shared__ int hist[NB];
  int t = threadIdx.x;
  if (t < NB) hist[t] = 0;
  __syncthreads();
  int base = blockIdx.x * 4096;
  int sv[8], dv[8];
  #pragma unroll
  for (int j = 0; j < 8; j++) {
    int e = base + j * 512 + t;
    bool ok = e < NE;
    dv[j] = ok ? dst[e] : -1;
    sv[j] = ok ? src[e] : 0;
    if (ok) atomicAdd(&hist[dv[j] >> BSH], 1);
  }
  __syncthreads();
  if (t < NB) {                       // reserve contiguous range in this bucket
    int c = hist[t];
    if (c) hist[t] = atomicAdd(&gcur[t], c);
  }
  __syncthreads();
  #pragma unroll
  for (int j = 0; j < 8; j++) {
    if (dv[j] >= 0) {
      int b = dv[j] >> BSH;
      int p = atomicAdd(&hist[b], 1);
      binned[p] = (unsigned int)sv[j] | ((unsigned int)(dv[j] & BMASK) << 17);
    }
  }
}

// ---------------- per-bucket CSR build: offs + deg + csr (L2-local scatter) ----
__global__ __launch_bounds__(512) void build_csr(const unsigned int* __restrict__ binned,
                                                 const int* __restrict__ gcur,
                                                 int* __restrict__ offs,
                                                 int* __restrict__ deg,
                                                 int* __restrict__ csr) {
  __shared__ int ncnt[256];
  __shared__ int sm[256];
  int t = threadIdx.x;
  int b = blockIdx.x;
  int beg = b * BCAP;
  int cntb = gcur[b] - beg;
  if (t < 256) ncnt[t] = 0;
  __syncthreads();
  for (int e = beg + t; e < beg + cntb; e += 512) atomicAdd(&ncnt[binned[e] >> 17], 1);
  __syncthreads();
  int s = 0;
  if (t < 256) { s = ncnt[t]; sm[t] = s; }
  __syncthreads();
  for (int off = 1; off < 256; off <<= 1) {
    int u = (t < 256 && t >= off) ? sm[t - off] : 0;
    __syncthreads();
    if (t < 256) sm[t] += u;
    __syncthreads();
  }
  if (t < 256) {
    int ex = sm[t] - s + beg;             // csr position of node t of this bucket
    int node = (b << BSH) + t;
    if (node < NN) { offs[node] = ex; deg[node] = s; }
    ncnt[t] = ex;                         // reuse as cursor
  }
  __syncthreads();
  for (int e = beg + t; e < beg + cntb; e += 512) {
    unsigned int u = binned[e];
    int p = atomicAdd(&ncnt[u >> 17], 1);
    csr[p] = (int)(u & 0x1FFFFu);
  }
}

// ---------------- aggregation: hsum[i] = h[i] + sum_{e->i} h[src_e]  (bf16) ----
__global__ __launch_bounds__(256) void aggregate(const unsigned short* __restrict__ h,
                                                 const int* __restrict__ offs,
                                                 const int* __restrict__ deg,
                                                 const int* __restrict__ csr,
                                                 unsigned short* __restrict__ out) {
  int wave = threadIdx.x >> 6;
  int lane = threadIdx.x & 63;
  int node = blockIdx.x * 4 + wave;
  if (node >= NN) return;
  int g  = lane >> 4;     // edge stream 0..3
  int sl = lane & 15;     // 16B column chunk
  int beg = offs[node];
  int dg  = deg[node];

  float acc[8];
  if (g == 0) {           // self contribution counted once
    us8 v = *(const us8*)(h + (size_t)node * HF + sl * 8);
    #pragma unroll
    for (int i = 0; i < 8; i++) acc[i] = b2f(v[i]);
  } else {
    #pragma unroll
    for (int i = 0; i < 8; i++) acc[i] = 0.f;
  }

  for (int e = beg + g; e < beg + dg; e += 4) {
    int s = csr[e];
    us8 v = *(const us8*)(h + (size_t)s * HF + sl * 8);
    #pragma unroll
    for (int i = 0; i < 8; i++) acc[i] += b2f(v[i]);
  }

  #pragma unroll
  for (int i = 0; i < 8; i++) {
    acc[i] += __shfl_xor(acc[i], 16, 64);
    acc[i] += __shfl_xor(acc[i], 32, 64);
  }
  if (g == 0) {
    us8 r;
    #pragma unroll
    for (int i = 0; i < 8; i++) r[i] = f2b(acc[i]);
    *(us8*)(out + (size_t)node * HF + sl * 8) = r;
  }
}

// =======================================================================
// Barrier-free MLP: weights loaded directly from global (fragment-swizzled,
// L1/L2-resident); activations wave-private (global -> regs -> LDS own rows).
// =======================================================================
__device__ __forceinline__ void mlp3_body(const unsigned short* __restrict__ in,
                                          unsigned short* Ab,
                                          const unsigned short* __restrict__ wt,
                                          const float* __restrict__ sarr,
                                          const float* __restrict__ tarr,
                                          int layer, int row0, int wave, int lane,
                                          bf16x8 af[4]) {
  int m = lane & 15, q = lane >> 4;
  int node = row0 + wave * 16 + m;
  int nclamp = (node < NN) ? node : 0;        // OOB rows compute garbage, never stored
  #pragma unroll
  for (int k0 = 0; k0 < 4; k0++)
    af[k0] = *(const bf16x8*)(in + (size_t)nclamp * HF + k0 * 32 + q * 8);

  const unsigned short* wbase = wt + layer * 3 * 16384;   // 16384 ushorts per sub
  #pragma unroll
  for (int sub = 0; sub < 3; sub++) {
    const unsigned short* wsub = wbase + sub * 16384;
    f32x4 acc[8];
    #pragma unroll
    for (int nt = 0; nt < 8; nt++) {
      acc[nt] = (f32x4){0.f, 0.f, 0.f, 0.f};
      #pragma unroll
      for (int k0 = 0; k0 < 4; k0++) {
        bf16x8 bf = *(const bf16x8*)(wsub + ((k0 * 8 + nt) * 64 + lane) * 8);
        acc[nt] = __builtin_amdgcn_mfma_f32_16x16x32_bf16(af[k0], bf, acc[nt], 0, 0, 0);
      }
    }
    const float* sp = sarr + (layer * 3 + sub) * HF;
    const float* tp = tarr + (layer * 3 + sub) * HF;
    #pragma unroll
    for (int nt = 0; nt < 8; nt++) {
      int c = nt * 16 + m;
      float sc = sp[c], sh = tp[c];
      #pragma unroll
      for (int i = 0; i < 4; i++) {
        int r = wave * 16 + q * 4 + i;     // C/D: col=lane&15, row=(lane>>4)*4+i
        float y = fmaxf(acc[nt][i] * sc + sh, 0.f);
        Ab[r * AP + c] = f2b(y);           // own rows: no barrier
      }
    }
    #pragma unroll
    for (int k0 = 0; k0 < 4; k0++)         // reload fragments (wave-local LDS RAW)
      af[k0] = *(const bf16x8*)&Ab[(wave * 16 + m) * AP + k0 * 32 + q * 8];
  }
}

// ---------------- layer-0 MLP: bf16 in -> bf16 out ----------------
__global__ __launch_bounds__(256) void mlp3(const unsigned short* __restrict__ in,
                                            unsigned short* __restrict__ out,
                                            const unsigned short* __restrict__ wt,
                                            const float* __restrict__ sarr,
                                            const float* __restrict__ tarr) {
  __shared__ unsigned short Ab[64 * AP];
  int t = threadIdx.x;
  int lane = t & 63, wave = t >> 6;
  int row0 = blockIdx.x * 64;
  bf16x8 af[4];
  mlp3_body(in, Ab, wt, sarr, tarr, 0, row0, wave, lane, af);

  // wave-local coalesced bf16 store of own 16 rows
  for (int it = 0; it < 4; it++) {
    int idx = it * 64 + lane;              // 4 rows x 16 chunks per pass
    int r = wave * 16 + (idx >> 4);
    int c = (idx & 15) << 3;
    int gr = row0 + r;
    if (gr < NN) *(us8*)(out + (size_t)gr * HF + c) = *(const us8*)&Ab[r * AP + c];
  }
}

// ---------------- layer-1 MLP + FC(128->64) + log_softmax ----------------
__global__ __launch_bounds__(256) void mlp3fc(const unsigned short* __restrict__ in,
                                              float* __restrict__ out,
                                              const unsigned short* __restrict__ wt,
                                              const float* __restrict__ sarr,
                                              const float* __restrict__ tarr,
                                              const unsigned short* __restrict__ wtf,
                                              const float* __restrict__ fc_b) {
  __shared__ unsigned short Ab[64 * AP];
  int t = threadIdx.x;
  int lane = t & 63, wave = t >> 6;
  int row0 = blockIdx.x * 64;
  int m = lane & 15, q = lane >> 4;
  bf16x8 af[4];
  mlp3_body(in, Ab, wt, sarr, tarr, 1, row0, wave, lane, af);

  // ---- FC 128->64 + log_softmax, all in registers ----
  f32x4 acc[4];
  #pragma unroll
  for (int nt = 0; nt < 4; nt++) {
    acc[nt] = (f32x4){0.f, 0.f, 0.f, 0.f};
    #pragma unroll
    for (int k0 = 0; k0 < 4; k0++) {
      bf16x8 bf = *(const bf16x8*)(wtf + ((k0 * 4 + nt) * 64 + lane) * 8);
      acc[nt] = __builtin_amdgcn_mfma_f32_16x16x32_bf16(af[k0], bf, acc[nt], 0, 0, 0);
    }
  }
  // logits: lane (q,m) holds rows q*4+i (i<4), cols nt*16+m
  float v[4][4];
  #pragma unroll
  for (int nt = 0; nt < 4; nt++) {
    float b = fc_b[nt * 16 + m];
    #pragma unroll
    for (int i = 0; i < 4; i++) v[nt][i] = acc[nt][i] + b;
  }
  float mx[4], sum[4];
  #pragma unroll
  for (int i = 0; i < 4; i++) {
    mx[i] = fmaxf(fmaxf(v[0][i], v[1][i]), fmaxf(v[2][i], v[3][i]));
    mx[i] = fmaxf(mx[i], __shfl_xor(mx[i], 1, 64));
    mx[i] = fmaxf(mx[i], __shfl_xor(mx[i], 2, 64));
    mx[i] = fmaxf(mx[i], __shfl_xor(mx[i], 4, 64));
    mx[i] = fmaxf(mx[i], __shfl_xor(mx[i], 8, 64));
    sum[i] = __expf(v[0][i] - mx[i]) + __expf(v[1][i] - mx[i])
           + __expf(v[2][i] - mx[i]) + __expf(v[3][i] - mx[i]);
    sum[i] += __shfl_xor(sum[i], 1, 64);
    sum[i] += __shfl_xor(sum[i], 2, 64);
    sum[i] += __shfl_xor(sum[i], 4, 64);
    sum[i] += __shfl_xor(sum[i], 8, 64);
    sum[i] = __logf(sum[i]) + mx[i];       // logsumexp
  }
  #pragma unroll
  for (int i = 0; i < 4; i++) {
    int gr = row0 + wave * 16 + q * 4 + i;
    if (gr < NN) {
      #pragma unroll
      for (int nt = 0; nt < 4; nt++)
        out[(size_t)gr * NC + nt * 16 + m] = v[nt][i] - sum[i];
    }
  }
}

// ---------------- launch ----------------
extern "C" void kernel_launch(void* const* d_in, const int* in_sizes, int n_in,
                              void* d_out, int out_size, void* d_ws, size_t ws_size,
                              hipStream_t stream) {
  const float* x      = (const float*)d_in[0];
  const int*   ei     = (const int*)d_in[1];
  const float* conv_w = (const float*)d_in[3];
  const float* conv_b = (const float*)d_in[4];
  const float* bn_g   = (const float*)d_in[5];
  const float* bn_b   = (const float*)d_in[6];
  const float* bn_m   = (const float*)d_in[7];
  const float* bn_v   = (const float*)d_in[8];
  const float* fc_w   = (const float*)d_in[9];
  const float* fc_b   = (const float*)d_in[10];
  float* out = (float*)d_out;

  const int* srcI = ei;        // edge_index[0]
  const int* dstI = ei + NE;   // edge_index[1]

  // workspace layout (~92 MiB)
  unsigned short* Xb   = (unsigned short*)d_ws;          // N*H bf16
  unsigned short* Abuf = Xb + (size_t)NN * HF;           // N*H bf16
  unsigned short* Bbuf = Abuf + (size_t)NN * HF;         // N*H bf16
  int* gcur   = (int*)(Bbuf + (size_t)NN * HF);          // NB (+pad)
  int* offs   = gcur + 512;                              // N+4
  int* deg    = offs + 100004;                           // N+4
  unsigned int* binned = (unsigned int*)(deg + 100004);  // NB*BCAP
  int* csr    = (int*)(binned + (size_t)NB * BCAP);      // NB*BCAP
  unsigned short* wt  = (unsigned short*)(csr + (size_t)NB * BCAP); // 6*16384 bf16 (swizzled)
  unsigned short* wtf = wt + 6 * HF * HF;                // 64*128 bf16 (swizzled)
  float* sarr = (float*)(wtf + HF * NC);                 // 6*128
  float* tarr = sarr + 6 * HF;                           // 6*128

  prologue<<<6250, 256, 0, stream>>>(x, Xb, conv_w, conv_b, bn_g, bn_b, bn_m, bn_v,
                                     fc_w, wt, wtf, sarr, tarr, gcur);
  bin_edges<<<NB, 512, 0, stream>>>(srcI, dstI, gcur, binned);
  build_csr<<<NB, 512, 0, stream>>>(binned, gcur, offs, deg, csr);

  aggregate<<<NN / 4, 256, 0, stream>>>(Xb, offs, deg, csr, Abuf);
  mlp3<<<(NN + 63) / 64, 256, 0, stream>>>(Abuf, Bbuf, wt, sarr, tarr);
  aggregate<<<NN / 4, 256, 0, stream>>>(Bbuf, offs, deg, csr, Abuf);
  mlp3fc<<<(NN + 63) / 64, 256, 0, stream>>>(Abuf, out, wt, sarr, tarr, wtf, fc_b);
}